// Round 6
// baseline (755.720 us; speedup 1.0000x reference)
//
#include <hip/hip_runtime.h>
#include <hip/hip_bf16.h>

#define S 768
#define CS 384
#define CP 128
#define E 16
#define PQ 4
#define PV 8
#define H 12
#define FDIM 2112          // H*(CP+E+PV*4)
#define OFF_PAIR 192       // H*E
#define OFF_PTS 1728       // +H*CP
#define OFF_NORM 2016      // +PV*H*3

typedef __hip_bfloat16 bf16;

__device__ __forceinline__ float b2f(bf16 x){ return __bfloat162float(x); }
__device__ __forceinline__ bf16 f2b(float x){ return __float2bfloat16(x); }
__device__ __forceinline__ float blo(unsigned u){ return __uint_as_float(u << 16); }
__device__ __forceinline__ float bhi(unsigned u){ return __uint_as_float(u & 0xffff0000u); }
__device__ __forceinline__ unsigned pk2(float a, float b){
  bf16 x = f2b(a), y = f2b(b);
  unsigned short ux = *reinterpret_cast<unsigned short*>(&x);
  unsigned short uy = *reinterpret_cast<unsigned short*>(&y);
  return (unsigned)ux | ((unsigned)uy << 16);
}

// ---------------- fused kernel A: k_proj (blocks 0..383) + k_wpair (384..2687) --
// wpair v3: coalesced reg-staging (lane-contiguous 16B units) -> XOR-swizzled
// ds_write -> conflict-free ds_read_b128. 32 threads/row (8 ch-groups x 4
// head-groups), Wb in registers, shfl-reduce over channel groups. Triple-buffered
// 2-ahead pipeline with raw s_barrier + lgkmcnt(0) (no full vmcnt drain).
__global__ __launch_bounds__(256) void k_proj_wpair(
    const float* __restrict__ sr, const float* __restrict__ rot, const float* __restrict__ trans,
    const float* __restrict__ Wq, const float* __restrict__ Wk, const float* __restrict__ Wv,
    const float* __restrict__ Wqp, const float* __restrict__ Wkp, const float* __restrict__ Wvp,
    float* __restrict__ q, float* __restrict__ kT, unsigned* __restrict__ vf2,
    float* __restrict__ lqp, float* __restrict__ lkpT,
    const float* __restrict__ pair, const float* __restrict__ Wb, float* __restrict__ wp)
{
  __shared__ __align__(16) float lds_all[6144];   // 24 KB: 3x1024 stage bufs + 3072 outbuf

  if (blockIdx.x < S/2){
    // ---- k_proj body: 2 residues/block; jp = blockIdx.x ----
    float (*srs)[CS] = (float(*)[CS])lds_all;          // 768 floats
    float (*Rs)[9]   = (float(*)[9])(lds_all + 768);   // 18
    float (*ts)[3]   = (float(*)[3])(lds_all + 786);   // 6
    int s0 = blockIdx.x*2;
    if (threadIdx.x < 96){
      int hh = threadIdx.x >> 3, c = 40 + (threadIdx.x & 7);
      vf2[((size_t)hh*(S/2) + blockIdx.x)*48 + c] = 0u;
    }
    for (int x = threadIdx.x; x < 2*CS; x += 256) ((float*)srs)[x] = sr[(size_t)s0*CS + x];
    if (threadIdx.x < 18) ((float*)Rs)[threadIdx.x] = rot[(size_t)s0*9 + threadIdx.x];
    if (threadIdx.x >= 64 && threadIdx.x < 70) ((float*)ts)[threadIdx.x-64] = trans[(size_t)s0*3 + threadIdx.x-64];
    __syncthreads();

    for (int task = threadIdx.x; task < 768; task += 256){
      if (task < 576){
        int which = task / 192;
        int he = task - which*192;
        int h = he >> 4, e = he & 15;
        const float* W = (which==0 ? Wq : (which==1 ? Wk : Wv)) + (size_t)he*CS;
        const float4* W4 = (const float4*)W;
        float acc[2] = {0.f,0.f};
        for (int cc = 0; cc < CS/4; ++cc){
          float4 w = W4[cc];
          #pragma unroll
          for (int r = 0; r < 2; ++r){
            const float* sp = srs[r] + cc*4;
            acc[r] += w.x*sp[0] + w.y*sp[1] + w.z*sp[2] + w.w*sp[3];
          }
        }
        if (which == 0){
          #pragma unroll
          for (int r = 0; r < 2; ++r) q[((size_t)h*S + s0+r)*E + e] = acc[r];
        } else if (which == 1){
          #pragma unroll
          for (int r = 0; r < 2; ++r) kT[((size_t)h*E + e)*S + s0+r] = acc[r];
        } else {
          vf2[((size_t)h*(S/2) + (s0>>1))*48 + e] = pk2(acc[0], acc[1]);
        }
      } else {
        int pt = task - 576;
        int h = pt >> 4, slot = pt & 15;
        int kind, p; const float* W;
        if (slot < 4)      { kind = 0; p = slot;     W = Wqp + (size_t)((h*PQ+p)*3)*CS; }
        else if (slot < 8) { kind = 1; p = slot - 4; W = Wkp + (size_t)((h*PQ+p)*3)*CS; }
        else               { kind = 2; p = slot - 8; W = Wvp + (size_t)((h*PV+p)*3)*CS; }
        const float4* W0 = (const float4*)W;
        const float4* W1 = (const float4*)(W + CS);
        const float4* W2 = (const float4*)(W + 2*CS);
        float a0[2] = {0,0}, a1[2] = {0,0}, a2[2] = {0,0};
        for (int cc = 0; cc < CS/4; ++cc){
          float4 w0 = W0[cc], w1 = W1[cc], w2 = W2[cc];
          #pragma unroll
          for (int r = 0; r < 2; ++r){
            const float* sp = srs[r] + cc*4;
            a0[r] += w0.x*sp[0] + w0.y*sp[1] + w0.z*sp[2] + w0.w*sp[3];
            a1[r] += w1.x*sp[0] + w1.y*sp[1] + w1.z*sp[2] + w1.w*sp[3];
            a2[r] += w2.x*sp[0] + w2.y*sp[1] + w2.z*sp[2] + w2.w*sp[3];
          }
        }
        float lv[2][3];
        #pragma unroll
        for (int r = 0; r < 2; ++r){
          int s = s0 + r;
          float l0 = Rs[r][0]*a0[r] + Rs[r][1]*a1[r] + Rs[r][2]*a2[r] + ts[r][0];
          float l1 = Rs[r][3]*a0[r] + Rs[r][4]*a1[r] + Rs[r][5]*a2[r] + ts[r][1];
          float l2 = Rs[r][6]*a0[r] + Rs[r][7]*a1[r] + Rs[r][8]*a2[r] + ts[r][2];
          if (kind == 0){ float* d = lqp + ((size_t)h*S + s)*12 + p*3; d[0]=l0; d[1]=l1; d[2]=l2; }
          else if (kind == 1){
            float* dst = lkpT + (size_t)h*12*S;
            dst[(size_t)(p*3+0)*S + s] = l0;
            dst[(size_t)(p*3+1)*S + s] = l1;
            dst[(size_t)(p*3+2)*S + s] = l2;
          } else {
            lv[r][0]=l0; lv[r][1]=l1; lv[r][2]=l2;
          }
        }
        if (kind == 2){
          size_t base = ((size_t)h*(S/2) + (s0>>1))*48 + 16 + p*3;
          vf2[base+0] = pk2(lv[0][0], lv[1][0]);
          vf2[base+1] = pk2(lv[0][1], lv[1][1]);
          vf2[base+2] = pk2(lv[0][2], lv[1][2]);
        }
      }
    }
  } else {
    // ---- k_wpair v3 ----
    int bwp = blockIdx.x - S/2;                // 0..2303
    size_t rowBase = (size_t)bwp * 256;        // 256 rows/block, 32 chunks of 8 rows
    int t    = threadIdx.x;
    int lane = t & 63;
    int hg   = __builtin_amdgcn_readfirstlane(t >> 6);   // wave id = head group
    int r    = lane & 7;                       // row within chunk (compute role)
    int cg   = (lane >> 3) & 7;                // channel group (16 channels)

    // Wb -> registers: 3 heads x 4 float4 (this thread's 16 channels)
    const float4* Wb4 = (const float4*)Wb;
    float4 wb0[4], wb1[4], wb2[4];
    #pragma unroll
    for (int u = 0; u < 4; ++u){
      wb0[u] = Wb4[(hg*3+0)*32 + cg*4 + u];
      wb1[u] = Wb4[(hg*3+1)*32 + cg*4 + u];
      wb2[u] = Wb4[(hg*3+2)*32 + cg*4 + u];
    }

    // staging role: thread t handles 16B unit (rs = t>>5, slot = t&31) of each chunk
    int rs   = t >> 5;                         // 0..7
    int slot = t & 31;
    int sw   = slot ^ rs;                      // swizzled 16B slot (involution)
    float* outw = lds_all + 3072;              // [12][256] results
    const uint4* psrc = (const uint4*)pair;    // 32 x 16B units per row

    // prologue: chunks 0,1 into regs; write chunk 0 -> buf0
    uint4 rA = psrc[(rowBase + rs)*32 + slot];
    uint4 rB = psrc[(rowBase + 8 + rs)*32 + slot];
    *((float4*)(lds_all) + rs*32 + sw) = *(float4*)&rA;     // compiler waits rA

    auto COMPUTE = [&](int c, int b){
      const float4* ch4 = (const float4*)(lds_all + b*1024);
      float a0 = 0.f, a1 = 0.f, a2 = 0.f;
      int rb32 = r*32, cb = cg*4;
      #pragma unroll
      for (int u = 0; u < 4; ++u){
        float4 p = ch4[rb32 + ((cb+u) ^ r)];
        a0 += wb0[u].x*p.x + wb0[u].y*p.y + wb0[u].z*p.z + wb0[u].w*p.w;
        a1 += wb1[u].x*p.x + wb1[u].y*p.y + wb1[u].z*p.z + wb1[u].w*p.w;
        a2 += wb2[u].x*p.x + wb2[u].y*p.y + wb2[u].z*p.z + wb2[u].w*p.w;
      }
      a0 += __shfl_xor(a0, 8); a0 += __shfl_xor(a0, 16); a0 += __shfl_xor(a0, 32);
      a1 += __shfl_xor(a1, 8); a1 += __shfl_xor(a1, 16); a1 += __shfl_xor(a1, 32);
      a2 += __shfl_xor(a2, 8); a2 += __shfl_xor(a2, 16); a2 += __shfl_xor(a2, 32);
      if (cg == 0){
        int row = c*8 + r;
        outw[(hg*3+0)*256 + row] = a0;
        outw[(hg*3+1)*256 + row] = a1;
        outw[(hg*3+2)*256 + row] = a2;
      }
    };

    for (int cc = 0; cc < 16; ++cc){
      int c0 = cc*2, c1 = cc*2 + 1;
      // iter c0: load chunk c0+2 -> rA; write chunk c0+1 (rB) -> buf (c0+1)%3
      if (c0+2 < 32) rA = psrc[(rowBase + (size_t)(c0+2)*8 + rs)*32 + slot];
      {
        int bw = (c0+1)%3;
        *((float4*)(lds_all + bw*1024) + rs*32 + sw) = *(float4*)&rB;
      }
      asm volatile("s_waitcnt lgkmcnt(0)" ::: "memory");
      __builtin_amdgcn_s_barrier();
      asm volatile("" ::: "memory");
      COMPUTE(c0, c0%3);
      // iter c1: load chunk c1+2 -> rB; write chunk c1+1 (rA) -> buf (c1+1)%3
      if (c1+2 < 32) rB = psrc[(rowBase + (size_t)(c1+2)*8 + rs)*32 + slot];
      if (c1+1 < 32){
        int bw = (c1+1)%3;
        *((float4*)(lds_all + bw*1024) + rs*32 + sw) = *(float4*)&rA;
      }
      asm volatile("s_waitcnt lgkmcnt(0)" ::: "memory");
      __builtin_amdgcn_s_barrier();
      asm volatile("" ::: "memory");
      COMPUTE(c1, c1%3);
    }
    __syncthreads();
    // coalesced flush: outw[h][256] -> wp[h][rowBase..rowBase+255]
    #pragma unroll
    for (int x = 0; x < 12; ++x)
      wp[(size_t)x*S*S + rowBase + t] = outw[x*256 + t];
  }
}

// ---------------- kernel 2: logits (wp + single + frame) + softmax --------------
__global__ __launch_bounds__(256) void k_attn(
    const float* __restrict__ wp,
    const float* __restrict__ q, const float* __restrict__ kT,
    const float* __restrict__ lqp, const float* __restrict__ lkpT,
    const float* __restrict__ gamma, bf16* __restrict__ ab)
{
  int i    = blockIdx.x / 3;
  int hg   = blockIdx.x % 3;
  int lane = threadIdx.x & 63;
  int w    = __builtin_amdgcn_readfirstlane(threadIdx.x >> 6);  // wave id, uniform
  int h    = hg*4 + w;

  __shared__ float lgs[4][S];   // 12 KB

  const float* qrow = q   + ((size_t)h*S + i)*E;   // wave-uniform -> s_load
  const float* lqr  = lqp + ((size_t)h*S + i)*12;  // wave-uniform -> s_load
  const float* wrow = wp  + ((size_t)h*S + i)*S;
  const float* kTh  = kT   + (size_t)h*E*S;
  const float* lkTh = lkpT + (size_t)h*12*S;
  float sf = -0.11785113019775793f * log1pf(__expf(gamma[h]));

  float qv[E];
  #pragma unroll
  for (int e = 0; e < E; ++e) qv[e] = qrow[e];
  float lq[12];
  #pragma unroll
  for (int x = 0; x < 12; ++x) lq[x] = lqr[x];

  float mloc = -1e30f;
  #pragma unroll 2
  for (int jj = 0; jj < 12; ++jj){
    int j = lane + jj*64;
    float d = 0.f;
    #pragma unroll
    for (int e = 0; e < E; ++e) d += qv[e]*kTh[(size_t)e*S + j];
    float fr = 0.f;
    #pragma unroll
    for (int x = 0; x < 12; ++x){ float df = lq[x] - lkTh[(size_t)x*S + j]; fr += df*df; }
    float lg = wrow[j] + 0.25f*d + sf*fr;
    lgs[w][j] = lg;
    mloc = fmaxf(mloc, lg);
  }
  #pragma unroll
  for (int mk = 1; mk < 64; mk <<= 1) mloc = fmaxf(mloc, __shfl_xor(mloc, mk));

  float sum = 0.f;
  #pragma unroll 3
  for (int jj = 0; jj < 12; ++jj){
    int j = lane + jj*64;
    float v = __expf(lgs[w][j] - mloc);
    lgs[w][j] = v;
    sum += v;
  }
  #pragma unroll
  for (int mk = 1; mk < 64; mk <<= 1) sum += __shfl_xor(sum, mk);
  float inv = 1.f/sum;

  size_t base = ((size_t)h*S + i)*S;
  #pragma unroll 3
  for (int jj = 0; jj < 12; ++jj){
    int j = lane + jj*64;
    ab[base + j] = f2b(lgs[w][j]*inv);
  }
}

// ---------------- fused kernel B: k_asum (blocks 0..383) + k_out_sv (384..2687) -
__global__ __launch_bounds__(256) void k_sv_asum(
    const bf16* __restrict__ ab, const unsigned* __restrict__ vf2,
    const float* __restrict__ rot, const float* __restrict__ trans,
    bf16* __restrict__ attnb, float* __restrict__ asumT)
{
  if (blockIdx.x < 384){
    // ---- k_asum body ----
    int h  = blockIdx.x / 32;
    int i0 = (blockIdx.x % 32) * 24;
    int t  = threadIdx.x;
    float a0 = 0.f, a1 = 0.f, a2 = 0.f;
    for (int i = i0; i < i0 + 24; ++i){
      const bf16* row = ab + ((size_t)h*S + i)*S;
      a0 += b2f(row[t]);
      a1 += b2f(row[t + 256]);
      a2 += b2f(row[t + 512]);
    }
    atomicAdd(&asumT[(t      )*H + h], a0);
    atomicAdd(&asumT[(t + 256)*H + h], a1);
    atomicAdd(&asumT[(t + 512)*H + h], a2);
  } else {
    // ---- k_out_sv body ----
    int bid  = blockIdx.x - 384;
    int h    = bid / (S/4);
    int i0   = (bid % (S/4))*4;
    int w    = threadIdx.x >> 6;
    int lane = threadIdx.x & 63;
    int i = i0 + w;
    const unsigned* arow = (const unsigned*)(ab + ((size_t)h*S + i)*S);  // 384 uints
    float acc = 0.f;
    if (lane < 48){
      const unsigned* vrow = vf2 + (size_t)h*(S/2)*48 + lane;
      float acc1 = 0.f;
      #pragma unroll 4
      for (int jp = 0; jp < S/2; jp += 2){
        unsigned ap0 = arow[jp], ap1 = arow[jp+1];
        unsigned vp0 = vrow[(size_t)jp*48], vp1 = vrow[(size_t)(jp+1)*48];
        acc  += blo(ap0)*blo(vp0) + bhi(ap0)*bhi(vp0);
        acc1 += blo(ap1)*blo(vp1) + bhi(ap1)*bhi(vp1);
      }
      acc += acc1;
    }
    __shared__ float ol[4][24];
    __shared__ float ogs[4][24];
    int pd = lane - 16;
    if (lane >= 16 && lane < 40) ol[w][pd] = acc;
    __syncthreads();
    if (lane < 16){
      attnb[(size_t)i*FDIM + h*E + lane] = f2b(acc);
    } else if (lane < 40){
      int p = pd/3, d = pd%3;
      float r0 = rot[(size_t)i*9 + 0 + d];
      float r1 = rot[(size_t)i*9 + 3 + d];
      float r2 = rot[(size_t)i*9 + 6 + d];
      float x0 = ol[w][p*3+0] - trans[i*3+0];
      float x1 = ol[w][p*3+1] - trans[i*3+1];
      float x2 = ol[w][p*3+2] - trans[i*3+2];
      float og = r0*x0 + r1*x1 + r2*x2;
      attnb[(size_t)i*FDIM + OFF_PTS + p*(H*3) + h*3 + d] = f2b(og);
      ogs[w][pd] = og;
    }
    __syncthreads();
    if (lane >= 16 && lane < 40 && (pd % 3) == 0){
      int p = pd/3;
      float g0 = ogs[w][p*3], g1 = ogs[w][p*3+1], g2 = ogs[w][p*3+2];
      attnb[(size_t)i*FDIM + OFF_NORM + p*H + h] = f2b(sqrtf(g0*g0 + g1*g1 + g2*g2));
    }
  }
}

// ---------------- kernel 5: o_pair[i,h,c] = sum_k asum[h,k]*pair[i,k,c] ---------
__global__ __launch_bounds__(512) void k_opair(const float* __restrict__ pair,
                                               const float* __restrict__ asumT,
                                               bf16* __restrict__ attnb)
{
  int i  = blockIdx.x;
  int t  = threadIdx.x;
  int c2 = t & 63;
  int g  = __builtin_amdgcn_readfirstlane(t >> 6);   // wave id 0..7, uniform
  float accx[H], accy[H];
  #pragma unroll
  for (int h = 0; h < H; ++h){ accx[h] = 0.f; accy[h] = 0.f; }
  const float2* prow = (const float2*)(pair + (size_t)i*S*CP) + c2;
  for (int kk = 0; kk < 96; ++kk){
    int kj = g*96 + kk;
    float2 pv = prow[(size_t)kj*64];
    const float* ap = asumT + kj*H;    // uniform -> s_load
    #pragma unroll
    for (int h = 0; h < H; ++h){
      accx[h] += ap[h]*pv.x;
      accy[h] += ap[h]*pv.y;
    }
  }
  __shared__ float part[8][H][CP];   // 48 KB
  #pragma unroll
  for (int h = 0; h < H; ++h)
    ((float2*)part[g][h])[c2] = make_float2(accx[h], accy[h]);
  __syncthreads();
  if (t < CP){
    #pragma unroll
    for (int h = 0; h < H; ++h){
      float s = part[0][h][t] + part[1][h][t] + part[2][h][t] + part[3][h][t]
              + part[4][h][t] + part[5][h][t] + part[6][h][t] + part[7][h][t];
      attnb[(size_t)i*FDIM + OFF_PAIR + h*CP + t] = f2b(s);
    }
  }
}

// ---------------- kernel 6: out += attn @ Wo^T (+bo), split-K x4 ---------------
__global__ __launch_bounds__(384) void k_final(const bf16* __restrict__ attnb,
                                               const float* __restrict__ Wo,
                                               const float* __restrict__ bo,
                                               float* __restrict__ out)
{
  int i0 = blockIdx.x*4;
  int ck = blockIdx.y;                     // 0..3
  int o  = threadIdx.x;
  const float4* wrow = (const float4*)(Wo + (size_t)o*FDIM) + ck*132;
  const unsigned* a0 = (const unsigned*)(attnb + (size_t)i0*FDIM) + ck*264;  // uniform
  const unsigned* a1 = a0 + FDIM/2;
  const unsigned* a2 = a1 + FDIM/2;
  const unsigned* a3 = a2 + FDIM/2;
  float c0=0.f, c1=0.f, c2=0.f, c3=0.f;
  for (int cc = 0; cc < 132; ++cc){
    float4 wv = wrow[cc];
    unsigned u;
    u = a0[cc*2]; c0 += wv.x*blo(u)+wv.y*bhi(u); u = a0[cc*2+1]; c0 += wv.z*blo(u)+wv.w*bhi(u);
    u = a1[cc*2]; c1 += wv.x*blo(u)+wv.y*bhi(u); u = a1[cc*2+1]; c1 += wv.z*blo(u)+wv.w*bhi(u);
    u = a2[cc*2]; c2 += wv.x*blo(u)+wv.y*bhi(u); u = a2[cc*2+1]; c2 += wv.z*blo(u)+wv.w*bhi(u);
    u = a3[cc*2]; c3 += wv.x*blo(u)+wv.y*bhi(u); u = a3[cc*2+1]; c3 += wv.z*blo(u)+wv.w*bhi(u);
  }
  if (ck == 0){
    float b = bo[o];
    c0 += b; c1 += b; c2 += b; c3 += b;
  }
  atomicAdd(&out[(size_t)(i0+0)*CS + o], c0);
  atomicAdd(&out[(size_t)(i0+1)*CS + o], c1);
  atomicAdd(&out[(size_t)(i0+2)*CS + o], c2);
  atomicAdd(&out[(size_t)(i0+3)*CS + o], c3);
}

extern "C" void kernel_launch(void* const* d_in, const int* in_sizes, int n_in,
                              void* d_out, int out_size, void* d_ws, size_t ws_size,
                              hipStream_t stream)
{
  const float* sr    = (const float*)d_in[0];
  const float* pair  = (const float*)d_in[1];
  const float* rot   = (const float*)d_in[2];
  const float* trans = (const float*)d_in[3];
  const float* Wq    = (const float*)d_in[4];
  const float* Wk    = (const float*)d_in[5];
  const float* Wv    = (const float*)d_in[6];
  const float* Wqp   = (const float*)d_in[7];
  const float* Wkp   = (const float*)d_in[8];
  const float* Wvp   = (const float*)d_in[9];
  const float* Wb    = (const float*)d_in[10];
  const float* Wo    = (const float*)d_in[11];
  const float* bo    = (const float*)d_in[12];
  const float* gamma = (const float*)d_in[13];

  // workspace layout (float units)
  float* ws    = (float*)d_ws;
  float*    q     = ws;                          // 147456
  float*    kT    = q    + 147456;               // 147456 [h][e][s]
  float*    lqp   = kT   + 147456;               // 110592 [h][s][12]
  float*    lkpT  = lqp  + 110592;               // 110592 [h][x][s]
  unsigned* vf2   = (unsigned*)(lkpT + 110592);  // 221184 uints [h][jp][48] bf16x2
  float*    asumT = (float*)(vf2 + 221184);      // 9216  [j][h]
  bf16*     ab    = (bf16*)(asumT + 9216);               // H*S*S bf16
  bf16*     attnb = (bf16*)(asumT + 9216 + 3538944);     // S*FDIM bf16
  float*    wp    = asumT + 9216 + 3538944 + 811008;     // H*S*S fp32 logits
  float* out = (float*)d_out;

  hipMemsetAsync(asumT, 0, (size_t)S*H*sizeof(float), stream);
  hipMemsetAsync(out,   0, (size_t)S*CS*sizeof(float), stream);
  k_proj_wpair<<<S/2 + (S*S)/256, 256, 0, stream>>>(sr, rot, trans, Wq, Wk, Wv, Wqp, Wkp, Wvp,
                                                    q, kT, vf2, lqp, lkpT, pair, Wb, wp);
  k_attn      <<<S*3,             256, 0, stream>>>(wp, q, kT, lqp, lkpT, gamma, ab);
  k_sv_asum   <<<384 + H*(S/4),   256, 0, stream>>>(ab, vf2, rot, trans, attnb, asumT);
  k_opair     <<<S,               512, 0, stream>>>(pair, asumT, attnb);
  k_final     <<<dim3(S/4, 4),    384, 0, stream>>>(attnb, Wo, bo, out);
}